// Round 3
// baseline (127.742 us; speedup 1.0000x reference)
//
#include <hip/hip_runtime.h>

// GNNDecoder: x_hat = GE[batch] @ node_w.T + node_b ; edge_hat = GE[batch[src]] @ edge_w.T + edge_b
// Restructured: per-graph projections P=[B,FN], Q=[B,FE] computed once (tiny GEMM),
// then outputs are pure row-gathers (memory-bound, 512MB nt-stores).
// R3: per-block contiguous slices (perfect balance, both phases per block) +
// LDS-staged graph ids (1 index load per row instead of 32/16; short dep chain).

#define H   256
#define FN  128
#define FE  64
#define GPB 8    // graphs per proj block
#define CH  256  // rows/edges per staging chunk

typedef float f4 __attribute__((ext_vector_type(4)));

__global__ __launch_bounds__(192) void proj_kernel(
    const float* __restrict__ ge,      // [B, H]
    const float* __restrict__ node_w,  // [FN, H]
    const float* __restrict__ node_b,  // [FN]
    const float* __restrict__ edge_w,  // [FE, H]
    const float* __restrict__ edge_b,  // [FE]
    float* __restrict__ P,             // [B, FN]
    float* __restrict__ Q)             // [B, FE]
{
    __shared__ float sge[GPB * H];
    const int t  = threadIdx.x;            // 0..191; waves 0,1 = node cols, wave 2 = edge cols
    const int g0 = blockIdx.x * GPB;

    const float4* ge4  = reinterpret_cast<const float4*>(ge + (size_t)g0 * H);
    float4*       sge4 = reinterpret_cast<float4*>(sge);
    for (int i = t; i < GPB * H / 4; i += 192) sge4[i] = ge4[i];
    __syncthreads();

    const float4* w4;
    float bias;
    if (t < FN) { w4 = reinterpret_cast<const float4*>(node_w + (size_t)t * H);      bias = node_b[t]; }
    else        { w4 = reinterpret_cast<const float4*>(edge_w + (size_t)(t-FN) * H); bias = edge_b[t-FN]; }

    float acc[GPB];
    #pragma unroll
    for (int g = 0; g < GPB; ++g) acc[g] = 0.f;

    #pragma unroll 4
    for (int k = 0; k < H / 4; ++k) {
        const float4 wv = w4[k];
        #pragma unroll
        for (int g = 0; g < GPB; ++g) {
            const float* s = sge + g * H + k * 4;   // same addr across lanes -> LDS broadcast
            acc[g] += wv.x * s[0] + wv.y * s[1] + wv.z * s[2] + wv.w * s[3];
        }
    }

    #pragma unroll
    for (int g = 0; g < GPB; ++g) {
        const float v = acc[g] + bias;
        if (t < FN) P[(size_t)(g0 + g) * FN + t]        = v;
        else        Q[(size_t)(g0 + g) * FE + (t - FN)] = v;
    }
}

// Both phases in every block; per-block contiguous slices; LDS-staged ids.
__global__ __launch_bounds__(256) void scatter_fused(
    const int* __restrict__ batch,     // [N]
    const int* __restrict__ src,       // edge_index row 0 (E)
    const f4* __restrict__ P4,         // [B*32]
    const f4* __restrict__ Q4,         // [B*16]
    f4* __restrict__ xout,             // [N*32]
    f4* __restrict__ eout,             // [E*16]
    int N, int E, int Bm1, int Nm1)
{
    __shared__ int sg[CH];
    const int b  = blockIdx.x;
    const int nb = gridDim.x;
    const int t  = threadIdx.x;

    // ---- node phase: rows [r0, r1) ----
    {
        const int r0 = (int)((long long)N * b / nb);
        const int r1 = (int)((long long)N * (b + 1) / nb);
        for (int c0 = r0; c0 < r1; c0 += CH) {
            const int rows = min(CH, r1 - c0);
            __syncthreads();
            if (t < rows) sg[t] = batch[c0 + t] & Bm1;
            __syncthreads();
            const int tot = rows << 5;          // rows * 32 f4
            f4* outb = xout + ((size_t)c0 << 5);
            for (int k = t; k < tot; k += 256) {
                const int r = k >> 5, c = k & 31;
                const int g = sg[r];
                __builtin_nontemporal_store(P4[(g << 5) + c], outb + k);
            }
        }
    }

    // ---- edge phase: edges [e0, e1) ----
    {
        const int e0 = (int)((long long)E * b / nb);
        const int e1 = (int)((long long)E * (b + 1) / nb);
        for (int c0 = e0; c0 < e1; c0 += CH) {
            const int es = min(CH, e1 - c0);
            __syncthreads();
            if (t < es) {
                int s = src[c0 + t];
                s = min(max(s, 0), Nm1);
                sg[t] = batch[s] & Bm1;
            }
            __syncthreads();
            const int tot = es << 4;            // es * 16 f4
            f4* outb = eout + ((size_t)c0 << 4);
            for (int k = t; k < tot; k += 256) {
                const int e = k >> 4, c = k & 15;
                const int g = sg[e];
                __builtin_nontemporal_store(Q4[(g << 4) + c], outb + k);
            }
        }
    }
}

extern "C" void kernel_launch(void* const* d_in, const int* in_sizes, int n_in,
                              void* d_out, int out_size, void* d_ws, size_t ws_size,
                              hipStream_t stream) {
    const float* ge     = (const float*)d_in[0];
    const int*   batch  = (const int*)  d_in[1];
    const int*   eidx   = (const int*)  d_in[2];
    const float* node_w = (const float*)d_in[3];
    const float* node_b = (const float*)d_in[4];
    const float* edge_w = (const float*)d_in[5];
    const float* edge_b = (const float*)d_in[6];

    const int B = in_sizes[0] / H;   // 4096
    const int N = in_sizes[1];       // 500000
    const int E = in_sizes[2] / 2;   // 1000000

    float* P = (float*)d_ws;                 // [B, FN]
    float* Q = P + (size_t)B * FN;           // [B, FE]

    float* x_hat = (float*)d_out;            // [N, FN]
    float* e_hat = x_hat + (size_t)N * FN;   // [E, FE]

    proj_kernel<<<B / GPB, 192, 0, stream>>>(ge, node_w, node_b, edge_w, edge_b, P, Q);

    scatter_fused<<<2048, 256, 0, stream>>>(
        batch, eidx, (const f4*)P, (const f4*)Q, (f4*)x_hat, (f4*)e_hat,
        N, E, B - 1, N - 1);
}